// Round 1
// baseline (112.500 us; speedup 1.0000x reference)
//
#include <hip/hip_runtime.h>

typedef __attribute__((ext_vector_type(8))) short bf8_t;   // 8 x bf16 (4 VGPRs)
typedef __attribute__((ext_vector_type(4))) float f4_t;    // 4 x f32 acc

static __device__ __forceinline__ short f2bf(float f) {
    union { float f; unsigned u; } v; v.f = f;
    unsigned r = v.u + 0x7fffu + ((v.u >> 16) & 1u);   // round-to-nearest-even
    return (short)(r >> 16);
}
static __device__ __forceinline__ float bf2f(short s) {
    union { unsigned u; float f; } v;
    v.u = ((unsigned)(unsigned short)s) << 16;
    return v.f;
}

#define NBLK 256u

// Device-scope grid barrier. Safe without cooperative launch because
// __launch_bounds__(256,2) caps VGPR<=256 and LDS is 13 KB -> every CU has
// capacity for >=2 blocks, so all 256 blocks (256 CUs) are co-resident under
// any dispatch order. Counters are zeroed by hipMemsetAsync each call, so
// workspace re-poisoning between iterations cannot corrupt them.
static __device__ __forceinline__ void grid_barrier(unsigned* cnt) {
    __syncthreads();
    if (threadIdx.x == 0) {
        __hip_atomic_fetch_add(cnt, 1u, __ATOMIC_RELEASE, __HIP_MEMORY_SCOPE_AGENT);
        while (__hip_atomic_load(cnt, __ATOMIC_ACQUIRE, __HIP_MEMORY_SCOPE_AGENT) < NBLK) {
            __builtin_amdgcn_s_sleep(1);
        }
        __threadfence();
    }
    __syncthreads();
}

// ---------------------------------------------------------------------------
// Single fused kernel, grid = 256 blocks x 256 threads.
//  phase 0: P [1024k][64n] fp32 -> Pt [64n][1024k] bf16      (1 elem/thread)
//  phase 1: t = x @ P via D = P^T x x^T, 16 rows/block, 4-wave K-split,
//           LDS reduce; wave 0 rounds to bf16, stores t + fp32 row norms
//           computed FROM the rounded bf16 (diagonal consistency).
//  phase 2: out[b,i,j] = n_i + n_j - 2*dot(t_i,t_j). 128x128 tile/block,
//           4 waves (2x2) of 64x64. MFMA operands SWAPPED vs previous
//           version: acc = mfma(A=t_j_frag, B=t_i_frag) so D row (quad*4+r)
//           indexes j -> each lane's f4 covers 4 consecutive j -> float4
//           stores (16/lane instead of 64 scalar stores/lane).
// ---------------------------------------------------------------------------
__global__ void __launch_bounds__(256, 2)
fused(const float* __restrict__ x, const float* __restrict__ P,
      float* __restrict__ out, short* __restrict__ Pt,
      short* __restrict__ t, float* __restrict__ norms,
      unsigned* __restrict__ bar)
{
    const int tid = threadIdx.x;
    const int bid = blockIdx.x;

    __shared__ float red[3][16][64];   // 12 KB, phase 1
    __shared__ float ni[128], nj[128]; // 1 KB,  phase 2

    // ---------------- phase 0: transpose P -> Pt (bf16) ----------------
    {
        int idx = bid * 256 + tid;          // 0..65535
        int n = idx >> 10, k = idx & 1023;
        Pt[idx] = f2bf(P[k * 64 + n]);      // write coalesced, read via L2
    }
    grid_barrier(bar + 0);

    // ---------------- phase 1: projection + norms ----------------
    {
        const int w    = tid >> 6;          // wave 0..3 (K-split)
        const int lane = tid & 63;
        const int nr   = lane & 15;
        const int quad = lane >> 4;
        const int row  = bid * 16 + nr;

        f4_t acc[4];
        #pragma unroll
        for (int mt = 0; mt < 4; mt++) acc[mt] = f4_t{0.f, 0.f, 0.f, 0.f};

        const float* xr = x + (size_t)row * 1024;
        #pragma unroll
        for (int kt = 0; kt < 8; kt++) {
            const int kb = w * 256 + kt * 32 + quad * 8;
            f4_t x0 = *(const f4_t*)(xr + kb);
            f4_t x1 = *(const f4_t*)(xr + kb + 4);
            bf8_t bfr;
            bfr[0] = f2bf(x0[0]); bfr[1] = f2bf(x0[1]);
            bfr[2] = f2bf(x0[2]); bfr[3] = f2bf(x0[3]);
            bfr[4] = f2bf(x1[0]); bfr[5] = f2bf(x1[1]);
            bfr[6] = f2bf(x1[2]); bfr[7] = f2bf(x1[3]);
            #pragma unroll
            for (int mt = 0; mt < 4; mt++) {
                bf8_t afr = *(const bf8_t*)(Pt + (size_t)(mt * 16 + nr) * 1024 + kb);
                acc[mt] = __builtin_amdgcn_mfma_f32_16x16x32_bf16(afr, bfr, acc[mt], 0, 0, 0);
            }
        }

        if (w > 0) {
            #pragma unroll
            for (int mt = 0; mt < 4; mt++)
                #pragma unroll
                for (int r = 0; r < 4; r++)
                    red[w - 1][mt * 4 + r][lane] = acc[mt][r];
        }
        __syncthreads();

        if (w == 0) {
            float nrm = 0.f;
            #pragma unroll
            for (int mt = 0; mt < 4; mt++) {
                float v0 = acc[mt][0] + red[0][mt*4+0][lane] + red[1][mt*4+0][lane] + red[2][mt*4+0][lane];
                float v1 = acc[mt][1] + red[0][mt*4+1][lane] + red[1][mt*4+1][lane] + red[2][mt*4+1][lane];
                float v2 = acc[mt][2] + red[0][mt*4+2][lane] + red[1][mt*4+2][lane] + red[2][mt*4+2][lane];
                float v3 = acc[mt][3] + red[0][mt*4+3][lane] + red[1][mt*4+3][lane] + red[2][mt*4+3][lane];
                short s0 = f2bf(v0), s1 = f2bf(v1), s2 = f2bf(v2), s3 = f2bf(v3);
                float b0 = bf2f(s0), b1 = bf2f(s1), b2 = bf2f(s2), b3 = bf2f(s3);
                nrm += b0*b0 + b1*b1 + b2*b2 + b3*b3;
                short4 sv; sv.x = s0; sv.y = s1; sv.z = s2; sv.w = s3;
                *(short4*)(t + (size_t)row * 64 + mt * 16 + quad * 4) = sv;
            }
            nrm += __shfl_xor(nrm, 16);
            nrm += __shfl_xor(nrm, 32);
            if (quad == 0) norms[row] = nrm;
        }
    }
    grid_barrier(bar + 32);   // second counter, 128 B away from the first

    // ---------------- phase 2: pairwise distances ----------------
    {
        const int b    = bid >> 6;
        const int ti   = (bid >> 3) & 7;
        const int tj   = bid & 7;
        const int w    = tid >> 6;
        const int lane = tid & 63;
        const int wy   = w >> 1, wx = w & 1;
        const int i0   = ti * 128 + wy * 64;
        const int j0   = tj * 128 + wx * 64;
        const int nr   = lane & 15, quad = lane >> 4;

        if (tid < 128) ni[tid]       = norms[b * 1024 + ti * 128 + tid];
        else           nj[tid - 128] = norms[b * 1024 + tj * 128 + (tid - 128)];
        __syncthreads();

        const short* tb = t + (size_t)b * 1024 * 64;

        f4_t acc[4][4];
        #pragma unroll
        for (int ia = 0; ia < 4; ia++)
            #pragma unroll
            for (int jb = 0; jb < 4; jb++) acc[ia][jb] = f4_t{0.f, 0.f, 0.f, 0.f};

        #pragma unroll
        for (int kt = 0; kt < 2; kt++) {
            const int kb = kt * 32 + quad * 8;
            bf8_t A[4], B[4];
            #pragma unroll
            for (int jb = 0; jb < 4; jb++)     // A operand <- j rows
                A[jb] = *(const bf8_t*)(tb + (size_t)(j0 + jb * 16 + nr) * 64 + kb);
            #pragma unroll
            for (int ia = 0; ia < 4; ia++)     // B operand <- i rows
                B[ia] = *(const bf8_t*)(tb + (size_t)(i0 + ia * 16 + nr) * 64 + kb);
            #pragma unroll
            for (int ia = 0; ia < 4; ia++)
                #pragma unroll
                for (int jb = 0; jb < 4; jb++)
                    acc[ia][jb] = __builtin_amdgcn_mfma_f32_16x16x32_bf16(A[jb], B[ia], acc[ia][jb], 0, 0, 0);
        }

        // D layout: col = nr -> i, row = quad*4 + reg -> j (4 consecutive j!)
        #pragma unroll
        for (int ia = 0; ia < 4; ia++) {
            const int i = i0 + ia * 16 + nr;
            const float niv = ni[wy * 64 + ia * 16 + nr];
            float* orow = out + ((size_t)b * 1024 + i) * 1024 + tj * 128;
            #pragma unroll
            for (int jb = 0; jb < 4; jb++) {
                const int jo = wx * 64 + jb * 16 + quad * 4;
                const float4 nv = *(const float4*)&nj[jo];   // broadcast, conflict-free
                f4_t a = acc[ia][jb];
                float4 v;
                v.x = niv + nv.x - 2.f * a[0];
                v.y = niv + nv.y - 2.f * a[1];
                v.z = niv + nv.z - 2.f * a[2];
                v.w = niv + nv.w - 2.f * a[3];
                *(float4*)(orow + jo) = v;                   // 16 B/lane, 64 B segments
            }
        }
    }
}

// ---------------------------------------------------------------------------
extern "C" void kernel_launch(void* const* d_in, const int* in_sizes, int n_in,
                              void* d_out, int out_size, void* d_ws, size_t ws_size,
                              hipStream_t stream) {
    const float* x = (const float*)d_in[0];   // [4,1024,1024] fp32
    const float* P = (const float*)d_in[1];   // [1024,64]     fp32
    float* out = (float*)d_out;               // [4,1024,1024] fp32

    // workspace: Pt bf16 (128 KB) | t bf16 (512 KB) | norms f32 (16 KB) | barrier
    short*    Pt    = (short*)d_ws;
    short*    t     = (short*)d_ws + 65536;
    float*    norms = (float*)((char*)d_ws + 640 * 1024);
    unsigned* bar   = (unsigned*)((char*)d_ws + (1 << 20));

    hipMemsetAsync(bar, 0, 256, stream);      // fresh barrier counters each call
    fused<<<256, 256, 0, stream>>>(x, P, out, Pt, t, norms, bar);
}

// Round 2
// 83.194 us; speedup vs baseline: 1.3523x; 1.3523x over previous
//
#include <hip/hip_runtime.h>

typedef __attribute__((ext_vector_type(8))) short bf8_t;   // 8 x bf16 (4 VGPRs)
typedef __attribute__((ext_vector_type(4))) float f4_t;    // 4 x f32

static __device__ __forceinline__ short f2bf(float f) {
    union { float f; unsigned u; } v; v.f = f;
    unsigned r = v.u + 0x7fffu + ((v.u >> 16) & 1u);   // round-to-nearest-even
    return (short)(r >> 16);
}
static __device__ __forceinline__ float bf2f(short s) {
    union { unsigned u; float f; } v;
    v.u = ((unsigned)(unsigned short)s) << 16;
    return v.f;
}

// ---------------------------------------------------------------------------
// K1: t = x @ P.  Fuses the P transpose: each block stages P^T (64 m x 1024 k,
// bf16, XOR-swizzled) into 128 KB LDS itself -- no separate transpose kernel,
// no grid barrier, no Pt global buffer.  8-wave K-split (128 K per wave),
// x fragments prefetched to registers BEFORE staging so HBM latency hides
// under the LLC-resident P reads.  LDS is reused (after syncthreads) for the
// cross-wave reduction.  Epilogue identical numerics to the passing version:
// t rounded to bf16, norms computed FROM the rounded values.
//
// LDS swizzle: elem (m,k) lives at byte m*2048 + ((2k) ^ ((m&7)<<4)).
// Fragment read: 16 lanes read rows m..m+15 at the same 16B column -> without
// swizzle all hit bank 0 (16-way conflict); with it, each consecutive 8-lane
// group covers all 8 16B-slots exactly once -> conflict-free.
// ---------------------------------------------------------------------------
__global__ void __launch_bounds__(512, 2)
proj_kernel(const float* __restrict__ x, const float* __restrict__ P,
            short* __restrict__ t, float* __restrict__ norms)
{
    const int tid  = threadIdx.x;
    const int w    = tid >> 6;          // wave 0..7 (K-split)
    const int lane = tid & 63;
    const int nr   = lane & 15;         // sample row within tile / m-lane
    const int quad = lane >> 4;
    const int row  = blockIdx.x * 16 + nr;

    __shared__ __align__(16) char smem[131072];   // P^T bf16, then reduce buf

    // ---- prefetch this wave's x fragments (16 rows x 128 K slice) ----
    const float* xr = x + (size_t)row * 1024;
    f4_t xv[4][2];
    #pragma unroll
    for (int kt = 0; kt < 4; kt++) {
        const int kb = w * 128 + kt * 32 + quad * 8;
        xv[kt][0] = *(const f4_t*)(xr + kb);
        xv[kt][1] = *(const f4_t*)(xr + kb + 4);
    }

    // ---- stage P -> LDS transposed bf16 (coalesced dwordx4 reads) ----
    // work item e = (kp, g): rows k=2kp,2kp+1, cols m=4g..4g+3
    #pragma unroll 4
    for (int it = 0; it < 16; ++it) {
        const int e  = it * 512 + tid;        // 0..8191
        const int g  = e & 15;
        const int kp = e >> 4;                // k-pair 0..511
        const f4_t p0 = *(const f4_t*)(P + (size_t)(kp * 2    ) * 64 + g * 4);
        const f4_t p1 = *(const f4_t*)(P + (size_t)(kp * 2 + 1) * 64 + g * 4);
        #pragma unroll
        for (int c = 0; c < 4; ++c) {
            const int m = g * 4 + c;
            const unsigned v = ((unsigned)(unsigned short)f2bf(p1[c]) << 16)
                             |  (unsigned)(unsigned short)f2bf(p0[c]);
            *(unsigned*)(smem + m * 2048 + ((kp * 4) ^ ((m & 7) << 4))) = v;
        }
    }
    __syncthreads();

    // ---- MFMA: acc[mt] = P^T(mt-slice) x x^T over this wave's K ----
    f4_t acc[4];
    #pragma unroll
    for (int mt = 0; mt < 4; mt++) acc[mt] = f4_t{0.f, 0.f, 0.f, 0.f};

    #pragma unroll
    for (int kt = 0; kt < 4; kt++) {
        bf8_t bfr;
        #pragma unroll
        for (int j = 0; j < 4; j++) {
            bfr[j]     = f2bf(xv[kt][0][j]);
            bfr[4 + j] = f2bf(xv[kt][1][j]);
        }
        const int colb = w * 256 + kt * 64 + quad * 16;   // byte col, 16B aligned
        #pragma unroll
        for (int mt = 0; mt < 4; mt++) {
            const int m = mt * 16 + nr;
            bf8_t afr = *(const bf8_t*)(smem + m * 2048 + (colb ^ ((nr & 7) << 4)));
            acc[mt] = __builtin_amdgcn_mfma_f32_16x16x32_bf16(afr, bfr, acc[mt], 0, 0, 0);
        }
    }
    __syncthreads();                  // all LDS frag reads done before reuse

    // ---- cross-wave reduction through (reused) LDS ----
    float* red = (float*)smem;        // [7][16][64]
    if (w > 0) {
        #pragma unroll
        for (int mt = 0; mt < 4; mt++)
            #pragma unroll
            for (int r = 0; r < 4; r++)
                red[((w - 1) * 16 + mt * 4 + r) * 64 + lane] = acc[mt][r];
    }
    __syncthreads();

    if (w == 0) {
        float nrm = 0.f;
        #pragma unroll
        for (int mt = 0; mt < 4; mt++) {
            float v0 = acc[mt][0], v1 = acc[mt][1], v2 = acc[mt][2], v3 = acc[mt][3];
            #pragma unroll
            for (int wi = 0; wi < 7; wi++) {
                v0 += red[(wi * 16 + mt * 4 + 0) * 64 + lane];
                v1 += red[(wi * 16 + mt * 4 + 1) * 64 + lane];
                v2 += red[(wi * 16 + mt * 4 + 2) * 64 + lane];
                v3 += red[(wi * 16 + mt * 4 + 3) * 64 + lane];
            }
            short s0 = f2bf(v0), s1 = f2bf(v1), s2 = f2bf(v2), s3 = f2bf(v3);
            float b0 = bf2f(s0), b1 = bf2f(s1), b2 = bf2f(s2), b3 = bf2f(s3);
            nrm += b0*b0 + b1*b1 + b2*b2 + b3*b3;
            short4 sv; sv.x = s0; sv.y = s1; sv.z = s2; sv.w = s3;
            // lane holds t[row][m] for m = mt*16 + quad*4 + {0..3}
            *(short4*)(t + (size_t)row * 64 + mt * 16 + quad * 4) = sv;
        }
        nrm += __shfl_xor(nrm, 16);
        nrm += __shfl_xor(nrm, 32);
        if (quad == 0) norms[row] = nrm;
    }
}

// ---------------------------------------------------------------------------
// K2: out[b,i,j] = n_i + n_j - 2*dot(t_i, t_j).  512 blocks (2/CU): 128i x 64j
// tile per block, 4 waves (2x2) of 64i x 32j.  MFMA operands swapped
// (A = t_j frag, B = t_i frag) so the D register quad holds 4 consecutive j
// -> float4 stores (8 per lane instead of 64 scalar dwords).
// ---------------------------------------------------------------------------
__global__ void __launch_bounds__(256, 2)
pairwise_kernel(const short* __restrict__ t, const float* __restrict__ norms,
                float* __restrict__ out)
{
    const int b    = blockIdx.y;
    const int ti   = blockIdx.x >> 4;    // 0..7   (128-row i panel)
    const int tj   = blockIdx.x & 15;    // 0..15  (64-col  j panel)
    const int tid  = threadIdx.x;
    const int w    = tid >> 6;
    const int lane = tid & 63;
    const int wy   = w >> 1, wx = w & 1;
    const int i0   = ti * 128 + wy * 64;
    const int j0   = tj * 64  + wx * 32;
    const int nr   = lane & 15, quad = lane >> 4;

    __shared__ float ni[128], nj[64];
    if (tid < 128)      ni[tid]       = norms[b * 1024 + ti * 128 + tid];
    else if (tid < 192) nj[tid - 128] = norms[b * 1024 + tj * 64 + (tid - 128)];
    __syncthreads();

    const short* tb = t + (size_t)b * 1024 * 64;

    f4_t acc[4][2];
    #pragma unroll
    for (int ia = 0; ia < 4; ia++)
        #pragma unroll
        for (int jb = 0; jb < 2; jb++) acc[ia][jb] = f4_t{0.f, 0.f, 0.f, 0.f};

    #pragma unroll
    for (int kt = 0; kt < 2; kt++) {
        const int kb = kt * 32 + quad * 8;
        bf8_t A[2], B[4];
        #pragma unroll
        for (int jb = 0; jb < 2; jb++)     // A operand <- j rows
            A[jb] = *(const bf8_t*)(tb + (size_t)(j0 + jb * 16 + nr) * 64 + kb);
        #pragma unroll
        for (int ia = 0; ia < 4; ia++)     // B operand <- i rows
            B[ia] = *(const bf8_t*)(tb + (size_t)(i0 + ia * 16 + nr) * 64 + kb);
        #pragma unroll
        for (int ia = 0; ia < 4; ia++)
            #pragma unroll
            for (int jb = 0; jb < 2; jb++)
                acc[ia][jb] = __builtin_amdgcn_mfma_f32_16x16x32_bf16(A[jb], B[ia], acc[ia][jb], 0, 0, 0);
    }

    // D layout: col = nr -> i, row = quad*4 + r -> j (4 consecutive j)
    #pragma unroll
    for (int ia = 0; ia < 4; ia++) {
        const int i = i0 + ia * 16 + nr;
        const float niv = ni[wy * 64 + ia * 16 + nr];
        float* orow = out + ((size_t)b * 1024 + i) * 1024 + tj * 64;
        #pragma unroll
        for (int jb = 0; jb < 2; jb++) {
            const int jo = wx * 32 + jb * 16 + quad * 4;
            const float4 nv = *(const float4*)&nj[jo];   // broadcast, conflict-free
            f4_t a = acc[ia][jb];
            float4 v;
            v.x = niv + nv.x - 2.f * a[0];
            v.y = niv + nv.y - 2.f * a[1];
            v.z = niv + nv.z - 2.f * a[2];
            v.w = niv + nv.w - 2.f * a[3];
            *(float4*)(orow + jo) = v;                   // 16 B/lane
        }
    }
}

// ---------------------------------------------------------------------------
extern "C" void kernel_launch(void* const* d_in, const int* in_sizes, int n_in,
                              void* d_out, int out_size, void* d_ws, size_t ws_size,
                              hipStream_t stream) {
    const float* x = (const float*)d_in[0];   // [4,1024,1024] fp32
    const float* P = (const float*)d_in[1];   // [1024,64]     fp32
    float* out = (float*)d_out;               // [4,1024,1024] fp32

    // workspace: t bf16 (512 KB) | norms f32 (16 KB)
    short* t     = (short*)d_ws;
    float* norms = (float*)((char*)d_ws + 512 * 1024);

    proj_kernel<<<256, 512, 0, stream>>>(x, P, t, norms);
    dim3 g2(128, 4);
    pairwise_kernel<<<g2, 256, 0, stream>>>(t, norms, out);
}

// Round 3
// 82.920 us; speedup vs baseline: 1.3567x; 1.0033x over previous
//
#include <hip/hip_runtime.h>

typedef __attribute__((ext_vector_type(8))) short bf8_t;   // 8 x bf16 (4 VGPRs)
typedef __attribute__((ext_vector_type(4))) float f4_t;    // 4 x f32

static __device__ __forceinline__ short f2bf(float f) {
    union { float f; unsigned u; } v; v.f = f;
    unsigned r = v.u + 0x7fffu + ((v.u >> 16) & 1u);   // round-to-nearest-even
    return (short)(r >> 16);
}
static __device__ __forceinline__ float bf2f(short s) {
    union { unsigned u; float f; } v;
    v.u = ((unsigned)(unsigned short)s) << 16;
    return v.f;
}

// ---------------------------------------------------------------------------
// K1: t = x @ P.  Unchanged from round 2 (passing): each block stages P^T
// (64 m x 1024 k bf16, XOR-swizzled) into LDS, 8-wave K-split, x fragments
// prefetched to registers BEFORE staging (16 dwordx4 in flight per lane ->
// ~128 KB/CU outstanding, HBM latency hidden under the L2-resident P stage).
// Epilogue: t rounded to bf16, norms computed FROM the rounded values.
// ---------------------------------------------------------------------------
__global__ void __launch_bounds__(512, 2)
proj_kernel(const float* __restrict__ x, const float* __restrict__ P,
            short* __restrict__ t, float* __restrict__ norms)
{
    const int tid  = threadIdx.x;
    const int w    = tid >> 6;          // wave 0..7 (K-split)
    const int lane = tid & 63;
    const int nr   = lane & 15;         // sample row within tile / m-lane
    const int quad = lane >> 4;
    const int row  = blockIdx.x * 16 + nr;

    __shared__ __align__(16) char smem[131072];   // P^T bf16, then reduce buf

    // ---- prefetch this wave's x fragments (16 rows x 128 K slice) ----
    const float* xr = x + (size_t)row * 1024;
    f4_t xv[4][2];
    #pragma unroll
    for (int kt = 0; kt < 4; kt++) {
        const int kb = w * 128 + kt * 32 + quad * 8;
        xv[kt][0] = *(const f4_t*)(xr + kb);
        xv[kt][1] = *(const f4_t*)(xr + kb + 4);
    }

    // ---- stage P -> LDS transposed bf16 (coalesced dwordx4 reads) ----
    #pragma unroll 4
    for (int it = 0; it < 16; ++it) {
        const int e  = it * 512 + tid;        // 0..8191
        const int g  = e & 15;
        const int kp = e >> 4;                // k-pair 0..511
        const f4_t p0 = *(const f4_t*)(P + (size_t)(kp * 2    ) * 64 + g * 4);
        const f4_t p1 = *(const f4_t*)(P + (size_t)(kp * 2 + 1) * 64 + g * 4);
        #pragma unroll
        for (int c = 0; c < 4; ++c) {
            const int m = g * 4 + c;
            const unsigned v = ((unsigned)(unsigned short)f2bf(p1[c]) << 16)
                             |  (unsigned)(unsigned short)f2bf(p0[c]);
            *(unsigned*)(smem + m * 2048 + ((kp * 4) ^ ((m & 7) << 4))) = v;
        }
    }
    __syncthreads();

    // ---- MFMA: acc[mt] = P^T(mt-slice) x x^T over this wave's K ----
    f4_t acc[4];
    #pragma unroll
    for (int mt = 0; mt < 4; mt++) acc[mt] = f4_t{0.f, 0.f, 0.f, 0.f};

    #pragma unroll
    for (int kt = 0; kt < 4; kt++) {
        bf8_t bfr;
        #pragma unroll
        for (int j = 0; j < 4; j++) {
            bfr[j]     = f2bf(xv[kt][0][j]);
            bfr[4 + j] = f2bf(xv[kt][1][j]);
        }
        const int colb = w * 256 + kt * 64 + quad * 16;   // byte col, 16B aligned
        #pragma unroll
        for (int mt = 0; mt < 4; mt++) {
            const int m = mt * 16 + nr;
            bf8_t afr = *(const bf8_t*)(smem + m * 2048 + (colb ^ ((nr & 7) << 4)));
            acc[mt] = __builtin_amdgcn_mfma_f32_16x16x32_bf16(afr, bfr, acc[mt], 0, 0, 0);
        }
    }
    __syncthreads();                  // all LDS frag reads done before reuse

    // ---- cross-wave reduction through (reused) LDS ----
    float* red = (float*)smem;        // [7][16][64]
    if (w > 0) {
        #pragma unroll
        for (int mt = 0; mt < 4; mt++)
            #pragma unroll
            for (int r = 0; r < 4; r++)
                red[((w - 1) * 16 + mt * 4 + r) * 64 + lane] = acc[mt][r];
    }
    __syncthreads();

    if (w == 0) {
        float nrm = 0.f;
        #pragma unroll
        for (int mt = 0; mt < 4; mt++) {
            float v0 = acc[mt][0], v1 = acc[mt][1], v2 = acc[mt][2], v3 = acc[mt][3];
            #pragma unroll
            for (int wi = 0; wi < 7; wi++) {
                v0 += red[(wi * 16 + mt * 4 + 0) * 64 + lane];
                v1 += red[(wi * 16 + mt * 4 + 1) * 64 + lane];
                v2 += red[(wi * 16 + mt * 4 + 2) * 64 + lane];
                v3 += red[(wi * 16 + mt * 4 + 3) * 64 + lane];
            }
            short s0 = f2bf(v0), s1 = f2bf(v1), s2 = f2bf(v2), s3 = f2bf(v3);
            float b0 = bf2f(s0), b1 = bf2f(s1), b2 = bf2f(s2), b3 = bf2f(s3);
            nrm += b0*b0 + b1*b1 + b2*b2 + b3*b3;
            short4 sv; sv.x = s0; sv.y = s1; sv.z = s2; sv.w = s3;
            *(short4*)(t + (size_t)row * 64 + mt * 16 + quad * 4) = sv;
        }
        nrm += __shfl_xor(nrm, 16);
        nrm += __shfl_xor(nrm, 32);
        if (quad == 0) norms[row] = nrm;
    }
}

// ---------------------------------------------------------------------------
// K2: out[b,i,j] = n_i + n_j - 2*dot(t_i, t_j).
// Round-3 restructure for LATENCY HIDING: 64x64 tiles -> 1024 blocks
// (4 blocks/CU co-resident, 16 waves/CU, VGPR capped 128 by launch_bounds).
// 4 waves (2x2) of 32x32; MFMA operands swapped (A = t_j frag, B = t_i frag)
// so the D register quad holds 4 consecutive j -> float4 stores (4/lane).
// Chunked XCD swizzle: the 16 blocks sharing an i-panel land on one XCD's L2
// (t = 512 KB fits any single L2) -> reads hit instead of cross-XCD misses.
// ---------------------------------------------------------------------------
__global__ void __launch_bounds__(256, 4)
pairwise_kernel(const short* __restrict__ t, const float* __restrict__ norms,
                float* __restrict__ out)
{
    const int b    = blockIdx.y;
    // bijective chunked XCD swizzle over 256 x-blocks: 32 consecutive per XCD
    const int swz  = (blockIdx.x & 7) * 32 + (blockIdx.x >> 3);
    const int ti   = swz >> 4;           // 0..15 (64-row i panel)
    const int tj   = swz & 15;           // 0..15 (64-col j panel)
    const int tid  = threadIdx.x;
    const int w    = tid >> 6;
    const int lane = tid & 63;
    const int wy   = w >> 1, wx = w & 1;
    const int i0   = ti * 64 + wy * 32;
    const int j0   = tj * 64 + wx * 32;
    const int nr   = lane & 15, quad = lane >> 4;

    __shared__ float ni[64], nj[64];
    if (tid < 64)       ni[tid]      = norms[b * 1024 + ti * 64 + tid];
    else if (tid < 128) nj[tid - 64] = norms[b * 1024 + tj * 64 + (tid - 64)];
    __syncthreads();

    const short* tb = t + (size_t)b * 1024 * 64;

    f4_t acc[2][2];
    #pragma unroll
    for (int ia = 0; ia < 2; ia++)
        #pragma unroll
        for (int jb = 0; jb < 2; jb++) acc[ia][jb] = f4_t{0.f, 0.f, 0.f, 0.f};

    #pragma unroll
    for (int kt = 0; kt < 2; kt++) {
        const int kb = kt * 32 + quad * 8;
        bf8_t A[2], B[2];
        #pragma unroll
        for (int jb = 0; jb < 2; jb++)     // A operand <- j rows
            A[jb] = *(const bf8_t*)(tb + (size_t)(j0 + jb * 16 + nr) * 64 + kb);
        #pragma unroll
        for (int ia = 0; ia < 2; ia++)     // B operand <- i rows
            B[ia] = *(const bf8_t*)(tb + (size_t)(i0 + ia * 16 + nr) * 64 + kb);
        #pragma unroll
        for (int ia = 0; ia < 2; ia++)
            #pragma unroll
            for (int jb = 0; jb < 2; jb++)
                acc[ia][jb] = __builtin_amdgcn_mfma_f32_16x16x32_bf16(A[jb], B[ia], acc[ia][jb], 0, 0, 0);
    }

    // D layout (verified passing r2): col = nr -> i, row = quad*4 + r -> j
    #pragma unroll
    for (int ia = 0; ia < 2; ia++) {
        const int i = i0 + ia * 16 + nr;
        const float niv = ni[wy * 32 + ia * 16 + nr];
        float* orow = out + ((size_t)b * 1024 + i) * 1024 + tj * 64;
        #pragma unroll
        for (int jb = 0; jb < 2; jb++) {
            const int jo = wx * 32 + jb * 16 + quad * 4;
            const float4 nv = *(const float4*)&nj[jo];   // broadcast, conflict-free
            f4_t a = acc[ia][jb];
            float4 v;
            v.x = niv + nv.x - 2.f * a[0];
            v.y = niv + nv.y - 2.f * a[1];
            v.z = niv + nv.z - 2.f * a[2];
            v.w = niv + nv.w - 2.f * a[3];
            *(float4*)(orow + jo) = v;                   // 16 B/lane
        }
    }
}

// ---------------------------------------------------------------------------
extern "C" void kernel_launch(void* const* d_in, const int* in_sizes, int n_in,
                              void* d_out, int out_size, void* d_ws, size_t ws_size,
                              hipStream_t stream) {
    const float* x = (const float*)d_in[0];   // [4,1024,1024] fp32
    const float* P = (const float*)d_in[1];   // [1024,64]     fp32
    float* out = (float*)d_out;               // [4,1024,1024] fp32

    // workspace: t bf16 (512 KB) | norms f32 (16 KB)
    short* t     = (short*)d_ws;
    float* norms = (float*)((char*)d_ws + 512 * 1024);

    proj_kernel<<<256, 512, 0, stream>>>(x, P, t, norms);
    dim3 g2(256, 4);
    pairwise_kernel<<<g2, 256, 0, stream>>>(t, norms, out);
}